// Round 1
// baseline (547.318 us; speedup 1.0000x reference)
//
#include <hip/hip_runtime.h>
#include <hip/hip_bf16.h>

#define N_NODES 100000
#define N_EDGES 500000

typedef __attribute__((ext_vector_type(8))) short  short8;   // 8 bf16 (4 VGPRs)
typedef __attribute__((ext_vector_type(4))) short  short4v;
typedef __attribute__((ext_vector_type(4))) float  float4v;

__device__ __forceinline__ unsigned short f2bf(float f) {
    union { float f; unsigned int u; } v; v.f = f;
    unsigned int u = v.u;
    unsigned int r = u + 0x7fffu + ((u >> 16) & 1u);  // RNE
    return (unsigned short)(r >> 16);
}
__device__ __forceinline__ float bf2f(unsigned short b) {
    union { unsigned int u; float f; } v; v.u = ((unsigned int)b) << 16;
    return v.f;
}

// async global->LDS, 16B per lane; lptr must follow wave-uniform-base + lane*16 order
__device__ __forceinline__ void gload_lds16(const unsigned short* g, unsigned short* l) {
    __builtin_amdgcn_global_load_lds(
        (const __attribute__((address_space(1))) unsigned int*)g,
        (__attribute__((address_space(3))) unsigned int*)l, 16, 0, 0);
}

// ---------------- z -> bf16 (zb lives in d_out's first 51.2MB; consumed before stage2 writes)
__global__ void zconv_kernel(const float* __restrict__ z, unsigned short* __restrict__ zb) {
    size_t i = ((size_t)blockIdx.x * 256 + threadIdx.x) * 8;   // 12500*256*8 = 25,600,000 exact
    float4v a = *(const float4v*)(z + i);
    float4v b = *(const float4v*)(z + i + 4);
    short8 o;
    o[0] = (short)f2bf(a.x); o[1] = (short)f2bf(a.y); o[2] = (short)f2bf(a.z); o[3] = (short)f2bf(a.w);
    o[4] = (short)f2bf(b.x); o[5] = (short)f2bf(b.y); o[6] = (short)f2bf(b.z); o[7] = (short)f2bf(b.w);
    *(short8*)(zb + i) = o;
}

// ---------------- prep: W1 -> W1cat bf16 [512][256], W2 -> bf16 [128][256]
__global__ void prep_kernel(const float* __restrict__ W1, const float* __restrict__ W2,
                            unsigned short* __restrict__ w1c, unsigned short* __restrict__ w2b) {
    int j = blockIdx.x, k = threadIdx.x;
    if (j < 512) {
        float v = (j < 256) ? W1[(size_t)j * 512 + k] : W1[(size_t)(j - 256) * 512 + 256 + k];
        w1c[(size_t)j * 256 + k] = f2bf(v);
    } else {
        int o = j - 512;
        w2b[(size_t)o * 256 + k] = f2bf(W2[(size_t)o * 256 + k]);
    }
}

// ---------------- stage 1: ZW[N,512](bf16) = zb[N,256] @ w1c^T, m97-style staging ----------
// LDS A/B tiles 128x64 bf16, unpadded, XOR-swizzled in 16B chunks: LDS[row][c] = G[row][c^(row&7)]
__launch_bounds__(256, 2)
__global__ void stage1_kernel(const unsigned short* __restrict__ zb,
                              const unsigned short* __restrict__ w1c,
                              unsigned short* __restrict__ ZW) {
    __shared__ unsigned short lds[128 * 136];       // 34816B; staging uses first 32KB
    unsigned short* At = lds;                       // [128][64]
    unsigned short* Bt = lds + 128 * 64;

    const int t    = threadIdx.x;
    const int lane = t & 63, wave = t >> 6;
    const int wm = wave >> 1, wn = wave & 1;
    const int l15 = lane & 15, quad = lane >> 4;
    const int mbase = blockIdx.x * 128, nbase = blockIdx.y * 128;

    // staging: inst (wave,q) covers rows wave*32+q*8 .. +8; lane lr=lane>>3 row, swizzled chunk
    const int lr = lane >> 3;
    const int cg = (lane & 7) ^ lr;                  // source chunk so LDS gets xor layout
    const unsigned short* ag[4]; const unsigned short* bg[4];
    unsigned short* al[4]; unsigned short* bl[4];
#pragma unroll
    for (int q = 0; q < 4; ++q) {
        int rA = wave * 32 + q * 8 + lr;
        int gA = mbase + rA; if (gA >= N_NODES) gA = N_NODES - 1;
        ag[q] = zb  + (size_t)gA * 256 + cg * 8;
        bg[q] = w1c + (size_t)(nbase + rA) * 256 + cg * 8;
        al[q] = At + (wave * 4 + q) * 512 + lane * 8;   // linear: base + lane*16B
        bl[q] = Bt + (wave * 4 + q) * 512 + lane * 8;
    }

    float4v acc[4][4];
    const float4v fz = {0.f, 0.f, 0.f, 0.f};
#pragma unroll
    for (int i = 0; i < 4; ++i)
#pragma unroll
        for (int j = 0; j < 4; ++j) acc[i][j] = fz;

    for (int kk = 0; kk < 256; kk += 64) {
        __syncthreads();
#pragma unroll
        for (int q = 0; q < 4; ++q) gload_lds16(ag[q] + kk, al[q]);
#pragma unroll
        for (int q = 0; q < 4; ++q) gload_lds16(bg[q] + kk, bl[q]);
        __syncthreads();   // drains vmcnt (global_load_lds) + lgkm

#pragma unroll
        for (int s = 0; s < 2; ++s) {
            const int ch = ((s * 4 + quad) ^ (l15 & 7)) * 8;   // de-swizzle (row&7 == l15&7)
            short8 af[4], bfr[4];
#pragma unroll
            for (int i = 0; i < 4; ++i)
                af[i] = *(const short8*)(At + (wm * 64 + i * 16 + l15) * 64 + ch);
#pragma unroll
            for (int j = 0; j < 4; ++j)
                bfr[j] = *(const short8*)(Bt + (wn * 64 + j * 16 + l15) * 64 + ch);
#pragma unroll
            for (int i = 0; i < 4; ++i)
#pragma unroll
                for (int j = 0; j < 4; ++j)
                    acc[i][j] = __builtin_amdgcn_mfma_f32_16x16x32_bf16(af[i], bfr[j], acc[i][j], 0, 0, 0);
        }
    }

    // epilogue: acc (row=quad*4+r, col=l15) -> LDS bf16 -> coalesced short8 stores
    __syncthreads();
#pragma unroll
    for (int i = 0; i < 4; ++i)
#pragma unroll
        for (int j = 0; j < 4; ++j) {
            int row = wm * 64 + i * 16 + quad * 4;
            int col = wn * 64 + j * 16 + l15;
#pragma unroll
            for (int r = 0; r < 4; ++r)
                lds[(row + r) * 136 + col] = f2bf(acc[i][j][r]);
        }
    __syncthreads();
    for (int c = t; c < 128 * 16; c += 256) {
        int row = c >> 4, ch2 = c & 15;
        int grow = mbase + row;
        if (grow < N_NODES)
            *(short8*)(ZW + (size_t)grow * 512 + nbase + ch2 * 8) =
                *(const short8*)(lds + row * 136 + ch2 * 8);
    }
}

// ---------------- stage 2: gather+bias+ReLU -> h (LDS bf16); out = h @ W2^T + b2 ------------
// EBLK=64: LDS = 64*264*2 + 512 = 34.3KB -> 4 blocks/CU (was 2 at EBLK=128). Latency-bound
// gather needs the occupancy; numerics identical to the EBLK=128 version.
#define H_PITCH 264
#define EBLK 64
__launch_bounds__(256, 4)
__global__ void stage2_kernel(const int* __restrict__ eidx, const unsigned short* __restrict__ ZW,
                              const float* __restrict__ b1, const unsigned short* __restrict__ w2b,
                              const float* __restrict__ b2, float* __restrict__ out) {
    __shared__ unsigned short h[EBLK * H_PITCH];  // 33792 B
    __shared__ int idx[128];                      // src[0..63], dst[64..127]
    const int t    = threadIdx.x;
    const int lane = t & 63, wave = t >> 6;
    const int l15 = lane & 15, quad = lane >> 4;
    const int wm = wave >> 1, wn = wave & 1;
    const int eb = blockIdx.x * EBLK;

    if (t < 128) {   // edge indices -> LDS (kills the per-pass idx->gather dependent chain)
        int e = eb + (t & 63); if (e >= N_EDGES) e = N_EDGES - 1;
        idx[t] = eidx[(t >> 6) * N_EDGES + e];
    }

    // W2 fragments kk=0..1 preloaded into regs (issued now, consumed after the gather phase).
    // Only 2 kk preloaded (32 VGPRs, not 64): at 16 waves/CU the later fragments' L1/L2-hit
    // latency is hidden by TLP, and we need headroom to fit 4 waves/SIMD (<=128 regs).
    const unsigned short* wr[4];
#pragma unroll
    for (int j = 0; j < 4; ++j)
        wr[j] = w2b + (size_t)(wn * 64 + j * 16 + l15) * 256 + quad * 8;
    short8 bfrag[4][2];
#pragma unroll
    for (int kk = 0; kk < 2; ++kk)
#pragma unroll
        for (int j = 0; j < 4; ++j)
            bfrag[j][kk] = *(const short8*)(wr[j] + kk * 32);

    __syncthreads();

    // ---- gather: 32 lanes x 16B per edge-row, depth-4 software pipeline (8 passes)
    const int lj = t & 31, er = t >> 5;
    float4v b1a = *(const float4v*)(b1 + lj * 8);
    float4v b1b = *(const float4v*)(b1 + lj * 8 + 4);
    const unsigned short* zs = ZW + lj * 8;
    const unsigned short* zd = ZW + 256 + lj * 8;

    short8 va[4], vb[4];
#pragma unroll
    for (int p = 0; p < 4; ++p) {
        int el = p * 8 + er;
        va[p] = *(const short8*)(zs + (size_t)idx[el] * 512);
        vb[p] = *(const short8*)(zd + (size_t)idx[64 + el] * 512);
    }
#pragma unroll
    for (int p = 0; p < 8; ++p) {
        int el = p * 8 + er;
        short8 xa = va[p & 3], xb = vb[p & 3];
        if (p < 4) {
            int el4 = el + 32;
            va[p & 3] = *(const short8*)(zs + (size_t)idx[el4] * 512);
            vb[p & 3] = *(const short8*)(zd + (size_t)idx[64 + el4] * 512);
        }
        short8 rv;
#pragma unroll
        for (int i = 0; i < 8; ++i) {
            float v = bf2f((unsigned short)xa[i]) + bf2f((unsigned short)xb[i])
                    + ((i < 4) ? b1a[i] : b1b[i - 4]);
            v = v > 0.f ? v : 0.f;
            rv[i] = (short)f2bf(v);
        }
        *(short8*)(h + el * H_PITCH + lj * 8) = rv;
    }
    __syncthreads();

    // ---- MFMA: A from h (LDS), B from regs (kk<2) / distance-1 prefetch (kk>=2)
    float4v acc[2][4];
    const float4v fz = {0.f, 0.f, 0.f, 0.f};
#pragma unroll
    for (int i = 0; i < 2; ++i)
#pragma unroll
        for (int j = 0; j < 4; ++j) acc[i][j] = fz;

    short8 pre[4];
#pragma unroll
    for (int j = 0; j < 4; ++j) pre[j] = *(const short8*)(wr[j] + 2 * 32);

#pragma unroll
    for (int kk = 0; kk < 8; ++kk) {
        short8 af[2];
#pragma unroll
        for (int i = 0; i < 2; ++i)
            af[i] = *(const short8*)(h + (wm * 32 + i * 16 + l15) * H_PITCH + kk * 32 + quad * 8);
        short8 bcur[4];
        if (kk < 2) {
#pragma unroll
            for (int j = 0; j < 4; ++j) bcur[j] = bfrag[j][kk];
        } else {
#pragma unroll
            for (int j = 0; j < 4; ++j) bcur[j] = pre[j];
            if (kk < 7) {
#pragma unroll
                for (int j = 0; j < 4; ++j) pre[j] = *(const short8*)(wr[j] + (kk + 1) * 32);
            }
        }
#pragma unroll
        for (int i = 0; i < 2; ++i)
#pragma unroll
            for (int j = 0; j < 4; ++j)
                acc[i][j] = __builtin_amdgcn_mfma_f32_16x16x32_bf16(af[i], bcur[j], acc[i][j], 0, 0, 0);
    }

    // ---- epilogue: + b2, fp32 stores
#pragma unroll
    for (int j = 0; j < 4; ++j) {
        int col = wn * 64 + j * 16 + l15;
        float bias = b2[col];
#pragma unroll
        for (int i = 0; i < 2; ++i) {
            int row0 = wm * 32 + i * 16 + quad * 4;
#pragma unroll
            for (int r = 0; r < 4; ++r) {
                int e = eb + row0 + r;
                if (e < N_EDGES) out[(size_t)e * 128 + col] = acc[i][j][r] + bias;
            }
        }
    }
}

// ---------------- fallback (ws too small): exact fp32 ----------------
__global__ void fallback_kernel(const float* __restrict__ z, const int* __restrict__ eidx,
                                const float* __restrict__ W1, const float* __restrict__ b1,
                                const float* __restrict__ W2, const float* __restrict__ b2,
                                float* __restrict__ out) {
    __shared__ float zs[512];
    __shared__ float hh[256];
    int e = blockIdx.x, t = threadIdx.x;
    int s = eidx[e], d = eidx[N_EDGES + e];
    zs[t]       = z[(size_t)s * 256 + t];
    zs[256 + t] = z[(size_t)d * 256 + t];
    __syncthreads();
    float a = b1[t];
    const float* wr = W1 + (size_t)t * 512;
    for (int k = 0; k < 512; ++k) a += zs[k] * wr[k];
    hh[t] = a > 0.f ? a : 0.f;
    __syncthreads();
    if (t < 128) {
        float o = b2[t];
        const float* w2r = W2 + (size_t)t * 256;
        for (int k = 0; k < 256; ++k) o += hh[k] * w2r[k];
        out[(size_t)e * 128 + t] = o;
    }
}

extern "C" void kernel_launch(void* const* d_in, const int* in_sizes, int n_in,
                              void* d_out, int out_size, void* d_ws, size_t ws_size,
                              hipStream_t stream) {
    const float* z    = (const float*)d_in[0];
    const int*   eidx = (const int*)d_in[1];
    const float* W1   = (const float*)d_in[2];
    const float* b1   = (const float*)d_in[3];
    const float* W2   = (const float*)d_in[4];
    const float* b2   = (const float*)d_in[5];
    float* out = (float*)d_out;

    const size_t zw_bytes = (size_t)N_NODES * 512 * 2;          // 102,400,000
    const size_t w1c_off  = zw_bytes;
    const size_t w2b_off  = w1c_off + (size_t)512 * 256 * 2;
    const size_t need     = w2b_off + (size_t)128 * 256 * 2;

    if (ws_size < need) {
        fallback_kernel<<<N_EDGES, 256, 0, stream>>>(z, eidx, W1, b1, W2, b2, out);
        return;
    }
    unsigned short* ZW  = (unsigned short*)d_ws;
    unsigned short* w1c = (unsigned short*)((char*)d_ws + w1c_off);
    unsigned short* w2b = (unsigned short*)((char*)d_ws + w2b_off);
    // zb scratch lives in d_out (51.2MB of 256MB); consumed by stage1 before stage2 writes out
    unsigned short* zb  = (unsigned short*)d_out;

    zconv_kernel<<<12500, 256, 0, stream>>>(z, zb);
    prep_kernel<<<640, 256, 0, stream>>>(W1, W2, w1c, w2b);
    stage1_kernel<<<dim3(782, 4), 256, 0, stream>>>(zb, w1c, ZW);
    stage2_kernel<<<(N_EDGES + EBLK - 1) / EBLK, 256, 0, stream>>>(eidx, ZW, b1, w2b, b2, out);
}

// Round 2
// 486.716 us; speedup vs baseline: 1.1245x; 1.1245x over previous
//
#include <hip/hip_runtime.h>
#include <hip/hip_bf16.h>

#define N_NODES 100000
#define N_EDGES 500000

typedef __attribute__((ext_vector_type(8))) short  short8;   // 8 bf16 (4 VGPRs)
typedef __attribute__((ext_vector_type(4))) short  short4v;
typedef __attribute__((ext_vector_type(4))) float  float4v;

__device__ __forceinline__ unsigned short f2bf(float f) {
    union { float f; unsigned int u; } v; v.f = f;
    unsigned int u = v.u;
    unsigned int r = u + 0x7fffu + ((u >> 16) & 1u);  // RNE
    return (unsigned short)(r >> 16);
}
__device__ __forceinline__ float bf2f(unsigned short b) {
    union { unsigned int u; float f; } v; v.u = ((unsigned int)b) << 16;
    return v.f;
}

// async global->LDS, 16B per lane; lptr must follow wave-uniform-base + lane*16 order
__device__ __forceinline__ void gload_lds16(const unsigned short* g, unsigned short* l) {
    __builtin_amdgcn_global_load_lds(
        (const __attribute__((address_space(1))) unsigned int*)g,
        (__attribute__((address_space(3))) unsigned int*)l, 16, 0, 0);
}

// ---------------- z -> bf16 (zb lives in d_out's first 51.2MB; consumed before stage2 writes)
__global__ void zconv_kernel(const float* __restrict__ z, unsigned short* __restrict__ zb) {
    size_t i = ((size_t)blockIdx.x * 256 + threadIdx.x) * 8;   // 12500*256*8 = 25,600,000 exact
    float4v a = *(const float4v*)(z + i);
    float4v b = *(const float4v*)(z + i + 4);
    short8 o;
    o[0] = (short)f2bf(a.x); o[1] = (short)f2bf(a.y); o[2] = (short)f2bf(a.z); o[3] = (short)f2bf(a.w);
    o[4] = (short)f2bf(b.x); o[5] = (short)f2bf(b.y); o[6] = (short)f2bf(b.z); o[7] = (short)f2bf(b.w);
    *(short8*)(zb + i) = o;
}

// ---------------- prep: W1 -> W1cat bf16 [512][256], W2 -> bf16 [128][256]
__global__ void prep_kernel(const float* __restrict__ W1, const float* __restrict__ W2,
                            unsigned short* __restrict__ w1c, unsigned short* __restrict__ w2b) {
    int j = blockIdx.x, k = threadIdx.x;
    if (j < 512) {
        float v = (j < 256) ? W1[(size_t)j * 512 + k] : W1[(size_t)(j - 256) * 512 + 256 + k];
        w1c[(size_t)j * 256 + k] = f2bf(v);
    } else {
        int o = j - 512;
        w2b[(size_t)o * 256 + k] = f2bf(W2[(size_t)o * 256 + k]);
    }
}

// ---------------- stage 1: ZW[N,512](bf16) = zb[N,256] @ w1c^T, m97-style staging ----------
// LDS A/B tiles 128x64 bf16, unpadded, XOR-swizzled in 16B chunks: LDS[row][c] = G[row][c^(row&7)]
__launch_bounds__(256, 2)
__global__ void stage1_kernel(const unsigned short* __restrict__ zb,
                              const unsigned short* __restrict__ w1c,
                              unsigned short* __restrict__ ZW) {
    __shared__ unsigned short lds[128 * 136];       // 34816B; staging uses first 32KB
    unsigned short* At = lds;                       // [128][64]
    unsigned short* Bt = lds + 128 * 64;

    const int t    = threadIdx.x;
    const int lane = t & 63, wave = t >> 6;
    const int wm = wave >> 1, wn = wave & 1;
    const int l15 = lane & 15, quad = lane >> 4;
    const int mbase = blockIdx.x * 128, nbase = blockIdx.y * 128;

    // staging: inst (wave,q) covers rows wave*32+q*8 .. +8; lane lr=lane>>3 row, swizzled chunk
    const int lr = lane >> 3;
    const int cg = (lane & 7) ^ lr;                  // source chunk so LDS gets xor layout
    const unsigned short* ag[4]; const unsigned short* bg[4];
    unsigned short* al[4]; unsigned short* bl[4];
#pragma unroll
    for (int q = 0; q < 4; ++q) {
        int rA = wave * 32 + q * 8 + lr;
        int gA = mbase + rA; if (gA >= N_NODES) gA = N_NODES - 1;
        ag[q] = zb  + (size_t)gA * 256 + cg * 8;
        bg[q] = w1c + (size_t)(nbase + rA) * 256 + cg * 8;
        al[q] = At + (wave * 4 + q) * 512 + lane * 8;   // linear: base + lane*16B
        bl[q] = Bt + (wave * 4 + q) * 512 + lane * 8;
    }

    float4v acc[4][4];
    const float4v fz = {0.f, 0.f, 0.f, 0.f};
#pragma unroll
    for (int i = 0; i < 4; ++i)
#pragma unroll
        for (int j = 0; j < 4; ++j) acc[i][j] = fz;

    for (int kk = 0; kk < 256; kk += 64) {
        __syncthreads();
#pragma unroll
        for (int q = 0; q < 4; ++q) gload_lds16(ag[q] + kk, al[q]);
#pragma unroll
        for (int q = 0; q < 4; ++q) gload_lds16(bg[q] + kk, bl[q]);
        __syncthreads();   // drains vmcnt (global_load_lds) + lgkm

#pragma unroll
        for (int s = 0; s < 2; ++s) {
            const int ch = ((s * 4 + quad) ^ (l15 & 7)) * 8;   // de-swizzle (row&7 == l15&7)
            short8 af[4], bfr[4];
#pragma unroll
            for (int i = 0; i < 4; ++i)
                af[i] = *(const short8*)(At + (wm * 64 + i * 16 + l15) * 64 + ch);
#pragma unroll
            for (int j = 0; j < 4; ++j)
                bfr[j] = *(const short8*)(Bt + (wn * 64 + j * 16 + l15) * 64 + ch);
#pragma unroll
            for (int i = 0; i < 4; ++i)
#pragma unroll
                for (int j = 0; j < 4; ++j)
                    acc[i][j] = __builtin_amdgcn_mfma_f32_16x16x32_bf16(af[i], bfr[j], acc[i][j], 0, 0, 0);
        }
    }

    // epilogue: acc (row=quad*4+r, col=l15) -> LDS bf16 -> coalesced short8 stores
    __syncthreads();
#pragma unroll
    for (int i = 0; i < 4; ++i)
#pragma unroll
        for (int j = 0; j < 4; ++j) {
            int row = wm * 64 + i * 16 + quad * 4;
            int col = wn * 64 + j * 16 + l15;
#pragma unroll
            for (int r = 0; r < 4; ++r)
                lds[(row + r) * 136 + col] = f2bf(acc[i][j][r]);
        }
    __syncthreads();
    for (int c = t; c < 128 * 16; c += 256) {
        int row = c >> 4, ch2 = c & 15;
        int grow = mbase + row;
        if (grow < N_NODES)
            *(short8*)(ZW + (size_t)grow * 512 + nbase + ch2 * 8) =
                *(const short8*)(lds + row * 136 + ch2 * 8);
    }
}

// ---------------- stage 2: gather+bias+ReLU -> h (LDS bf16); out = h @ W2^T + b2 ------------
// Latency x MLP bound: all 16 gather loads issued up front (8KB in flight/wave), and the
// out-tile is staged through LDS and stored with nontemporal float4 (full-line writes that
// don't evict ZW from L3 -> fewer HBM re-fetches of ZW, lower average gather latency).
#define H_PITCH 264
#define EBLK 64
__launch_bounds__(256, 4)
__global__ void stage2_kernel(const int* __restrict__ eidx, const unsigned short* __restrict__ ZW,
                              const float* __restrict__ b1, const unsigned short* __restrict__ w2b,
                              const float* __restrict__ b2, float* __restrict__ out) {
    __shared__ unsigned short h[EBLK * H_PITCH];  // 33792 B; reused as [64][132] f32 for epilogue
    __shared__ int idx[128];                      // src[0..63], dst[64..127]
    float* hf = (float*)h;
    const int t    = threadIdx.x;
    const int lane = t & 63, wave = t >> 6;
    const int l15 = lane & 15, quad = lane >> 4;
    const int wm = wave >> 1, wn = wave & 1;
    const int eb = blockIdx.x * EBLK;

    if (t < 128) {   // edge indices -> LDS (kills the per-pass idx->gather dependent chain)
        int e = eb + (t & 63); if (e >= N_EDGES) e = N_EDGES - 1;
        idx[t] = eidx[(t >> 6) * N_EDGES + e];
    }
    __syncthreads();

    // ---- gather: 32 lanes x 16B per edge-row; ALL 16 loads in flight before first use
    const int lj = t & 31, er = t >> 5;
    float4v b1a = *(const float4v*)(b1 + lj * 8);
    float4v b1b = *(const float4v*)(b1 + lj * 8 + 4);
    const unsigned short* zs = ZW + lj * 8;
    const unsigned short* zd = ZW + 256 + lj * 8;

    short8 va[8], vb[8];
#pragma unroll
    for (int p = 0; p < 8; ++p) {
        int el = p * 8 + er;
        va[p] = *(const short8*)(zs + (size_t)idx[el] * 512);
        vb[p] = *(const short8*)(zd + (size_t)idx[64 + el] * 512);
    }
#pragma unroll
    for (int p = 0; p < 8; ++p) {
        int el = p * 8 + er;
        short8 xa = va[p], xb = vb[p];
        short8 rv;
#pragma unroll
        for (int i = 0; i < 8; ++i) {
            float v = bf2f((unsigned short)xa[i]) + bf2f((unsigned short)xb[i])
                    + ((i < 4) ? b1a[i] : b1b[i - 4]);
            v = v > 0.f ? v : 0.f;
            rv[i] = (short)f2bf(v);
        }
        *(short8*)(h + el * H_PITCH + lj * 8) = rv;
    }
    __syncthreads();

    // ---- MFMA: A from h (LDS), B from w2b with depth-2 register prefetch (L2-hot)
    const unsigned short* wr[4];
#pragma unroll
    for (int j = 0; j < 4; ++j)
        wr[j] = w2b + (size_t)(wn * 64 + j * 16 + l15) * 256 + quad * 8;

    float4v acc[2][4];
    const float4v fz = {0.f, 0.f, 0.f, 0.f};
#pragma unroll
    for (int i = 0; i < 2; ++i)
#pragma unroll
        for (int j = 0; j < 4; ++j) acc[i][j] = fz;

    short8 pre[4][2];
#pragma unroll
    for (int kk = 0; kk < 2; ++kk)
#pragma unroll
        for (int j = 0; j < 4; ++j) pre[j][kk] = *(const short8*)(wr[j] + kk * 32);

#pragma unroll
    for (int kk = 0; kk < 8; ++kk) {
        short8 af[2];
#pragma unroll
        for (int i = 0; i < 2; ++i)
            af[i] = *(const short8*)(h + (wm * 32 + i * 16 + l15) * H_PITCH + kk * 32 + quad * 8);
        short8 bcur[4];
#pragma unroll
        for (int j = 0; j < 4; ++j) bcur[j] = pre[j][kk & 1];
        if (kk < 6) {
#pragma unroll
            for (int j = 0; j < 4; ++j) pre[j][kk & 1] = *(const short8*)(wr[j] + (kk + 2) * 32);
        }
#pragma unroll
        for (int i = 0; i < 2; ++i)
#pragma unroll
            for (int j = 0; j < 4; ++j)
                acc[i][j] = __builtin_amdgcn_mfma_f32_16x16x32_bf16(af[i], bcur[j], acc[i][j], 0, 0, 0);
    }

    // ---- epilogue: acc + b2 -> LDS f32 [64][132] -> coalesced nontemporal float4 stores
    __syncthreads();   // h reads done; safe to overwrite as f32
#pragma unroll
    for (int j = 0; j < 4; ++j) {
        int col = wn * 64 + j * 16 + l15;
        float bias = b2[col];
#pragma unroll
        for (int i = 0; i < 2; ++i) {
            int row0 = wm * 32 + i * 16 + quad * 4;
#pragma unroll
            for (int r = 0; r < 4; ++r)
                hf[(row0 + r) * 132 + col] = acc[i][j][r] + bias;
        }
    }
    __syncthreads();
#pragma unroll
    for (int pass = 0; pass < 8; ++pass) {
        int it  = pass * 256 + t;
        int row = it >> 5, c4 = (it & 31) * 4;
        int e = eb + row;
        if (e < N_EDGES) {
            float4v v = *(const float4v*)(hf + row * 132 + c4);
            __builtin_nontemporal_store(v, (float4v*)(out + (size_t)e * 128 + c4));
        }
    }
}

// ---------------- fallback (ws too small): exact fp32 ----------------
__global__ void fallback_kernel(const float* __restrict__ z, const int* __restrict__ eidx,
                                const float* __restrict__ W1, const float* __restrict__ b1,
                                const float* __restrict__ W2, const float* __restrict__ b2,
                                float* __restrict__ out) {
    __shared__ float zs[512];
    __shared__ float hh[256];
    int e = blockIdx.x, t = threadIdx.x;
    int s = eidx[e], d = eidx[N_EDGES + e];
    zs[t]       = z[(size_t)s * 256 + t];
    zs[256 + t] = z[(size_t)d * 256 + t];
    __syncthreads();
    float a = b1[t];
    const float* wr = W1 + (size_t)t * 512;
    for (int k = 0; k < 512; ++k) a += zs[k] * wr[k];
    hh[t] = a > 0.f ? a : 0.f;
    __syncthreads();
    if (t < 128) {
        float o = b2[t];
        const float* w2r = W2 + (size_t)t * 256;
        for (int k = 0; k < 256; ++k) o += hh[k] * w2r[k];
        out[(size_t)e * 128 + t] = o;
    }
}

extern "C" void kernel_launch(void* const* d_in, const int* in_sizes, int n_in,
                              void* d_out, int out_size, void* d_ws, size_t ws_size,
                              hipStream_t stream) {
    const float* z    = (const float*)d_in[0];
    const int*   eidx = (const int*)d_in[1];
    const float* W1   = (const float*)d_in[2];
    const float* b1   = (const float*)d_in[3];
    const float* W2   = (const float*)d_in[4];
    const float* b2   = (const float*)d_in[5];
    float* out = (float*)d_out;

    const size_t zw_bytes = (size_t)N_NODES * 512 * 2;          // 102,400,000
    const size_t w1c_off  = zw_bytes;
    const size_t w2b_off  = w1c_off + (size_t)512 * 256 * 2;
    const size_t need     = w2b_off + (size_t)128 * 256 * 2;

    if (ws_size < need) {
        fallback_kernel<<<N_EDGES, 256, 0, stream>>>(z, eidx, W1, b1, W2, b2, out);
        return;
    }
    unsigned short* ZW  = (unsigned short*)d_ws;
    unsigned short* w1c = (unsigned short*)((char*)d_ws + w1c_off);
    unsigned short* w2b = (unsigned short*)((char*)d_ws + w2b_off);
    // zb scratch lives in d_out (51.2MB of 256MB); consumed by stage1 before stage2 writes out
    unsigned short* zb  = (unsigned short*)d_out;

    zconv_kernel<<<12500, 256, 0, stream>>>(z, zb);
    prep_kernel<<<640, 256, 0, stream>>>(W1, W2, w1c, w2b);
    stage1_kernel<<<dim3(782, 4), 256, 0, stream>>>(zb, w1c, ZW);
    stage2_kernel<<<(N_EDGES + EBLK - 1) / EBLK, 256, 0, stream>>>(eidx, ZW, b1, w2b, b2, out);
}

// Round 3
// 448.338 us; speedup vs baseline: 1.2208x; 1.0856x over previous
//
#include <hip/hip_runtime.h>
#include <hip/hip_bf16.h>

#define N_NODES 100000
#define N_EDGES 500000

typedef __attribute__((ext_vector_type(8))) short  short8;   // 8 bf16 (4 VGPRs)
typedef __attribute__((ext_vector_type(4))) short  short4v;
typedef __attribute__((ext_vector_type(4))) float  float4v;

__device__ __forceinline__ unsigned short f2bf(float f) {
    union { float f; unsigned int u; } v; v.f = f;
    unsigned int u = v.u;
    unsigned int r = u + 0x7fffu + ((u >> 16) & 1u);  // RNE
    return (unsigned short)(r >> 16);
}
__device__ __forceinline__ float bf2f(unsigned short b) {
    union { unsigned int u; float f; } v; v.u = ((unsigned int)b) << 16;
    return v.f;
}

// async global->LDS, 16B per lane; lptr must follow wave-uniform-base + lane*16 order
__device__ __forceinline__ void gload_lds16(const unsigned short* g, unsigned short* l) {
    __builtin_amdgcn_global_load_lds(
        (const __attribute__((address_space(1))) unsigned int*)g,
        (__attribute__((address_space(3))) unsigned int*)l, 16, 0, 0);
}

// ---------------- z -> bf16 (zb lives in d_out's first 51.2MB; consumed before stage2 writes)
__global__ void zconv_kernel(const float* __restrict__ z, unsigned short* __restrict__ zb) {
    size_t i = ((size_t)blockIdx.x * 256 + threadIdx.x) * 8;   // 12500*256*8 = 25,600,000 exact
    float4v a = *(const float4v*)(z + i);
    float4v b = *(const float4v*)(z + i + 4);
    short8 o;
    o[0] = (short)f2bf(a.x); o[1] = (short)f2bf(a.y); o[2] = (short)f2bf(a.z); o[3] = (short)f2bf(a.w);
    o[4] = (short)f2bf(b.x); o[5] = (short)f2bf(b.y); o[6] = (short)f2bf(b.z); o[7] = (short)f2bf(b.w);
    *(short8*)(zb + i) = o;
}

// ---------------- prep: W1 -> W1cat bf16 [512][256], W2 -> bf16 [128][256]
__global__ void prep_kernel(const float* __restrict__ W1, const float* __restrict__ W2,
                            unsigned short* __restrict__ w1c, unsigned short* __restrict__ w2b) {
    int j = blockIdx.x, k = threadIdx.x;
    if (j < 512) {
        float v = (j < 256) ? W1[(size_t)j * 512 + k] : W1[(size_t)(j - 256) * 512 + 256 + k];
        w1c[(size_t)j * 256 + k] = f2bf(v);
    } else {
        int o = j - 512;
        w2b[(size_t)o * 256 + k] = f2bf(W2[(size_t)o * 256 + k]);
    }
}

// ---------------- stage 1: ZW[N,512](bf16) = zb[N,256] @ w1c^T, m97-style staging ----------
// LDS A/B tiles 128x64 bf16, unpadded, XOR-swizzled in 16B chunks: LDS[row][c] = G[row][c^(row&7)]
__launch_bounds__(256, 2)
__global__ void stage1_kernel(const unsigned short* __restrict__ zb,
                              const unsigned short* __restrict__ w1c,
                              unsigned short* __restrict__ ZW) {
    __shared__ unsigned short lds[128 * 136];       // 34816B; staging uses first 32KB
    unsigned short* At = lds;                       // [128][64]
    unsigned short* Bt = lds + 128 * 64;

    const int t    = threadIdx.x;
    const int lane = t & 63, wave = t >> 6;
    const int wm = wave >> 1, wn = wave & 1;
    const int l15 = lane & 15, quad = lane >> 4;
    const int mbase = blockIdx.x * 128, nbase = blockIdx.y * 128;

    // staging: inst (wave,q) covers rows wave*32+q*8 .. +8; lane lr=lane>>3 row, swizzled chunk
    const int lr = lane >> 3;
    const int cg = (lane & 7) ^ lr;                  // source chunk so LDS gets xor layout
    const unsigned short* ag[4]; const unsigned short* bg[4];
    unsigned short* al[4]; unsigned short* bl[4];
#pragma unroll
    for (int q = 0; q < 4; ++q) {
        int rA = wave * 32 + q * 8 + lr;
        int gA = mbase + rA; if (gA >= N_NODES) gA = N_NODES - 1;
        ag[q] = zb  + (size_t)gA * 256 + cg * 8;
        bg[q] = w1c + (size_t)(nbase + rA) * 256 + cg * 8;
        al[q] = At + (wave * 4 + q) * 512 + lane * 8;   // linear: base + lane*16B
        bl[q] = Bt + (wave * 4 + q) * 512 + lane * 8;
    }

    float4v acc[4][4];
    const float4v fz = {0.f, 0.f, 0.f, 0.f};
#pragma unroll
    for (int i = 0; i < 4; ++i)
#pragma unroll
        for (int j = 0; j < 4; ++j) acc[i][j] = fz;

    for (int kk = 0; kk < 256; kk += 64) {
        __syncthreads();
#pragma unroll
        for (int q = 0; q < 4; ++q) gload_lds16(ag[q] + kk, al[q]);
#pragma unroll
        for (int q = 0; q < 4; ++q) gload_lds16(bg[q] + kk, bl[q]);
        __syncthreads();   // drains vmcnt (global_load_lds) + lgkm

#pragma unroll
        for (int s = 0; s < 2; ++s) {
            const int ch = ((s * 4 + quad) ^ (l15 & 7)) * 8;   // de-swizzle (row&7 == l15&7)
            short8 af[4], bfr[4];
#pragma unroll
            for (int i = 0; i < 4; ++i)
                af[i] = *(const short8*)(At + (wm * 64 + i * 16 + l15) * 64 + ch);
#pragma unroll
            for (int j = 0; j < 4; ++j)
                bfr[j] = *(const short8*)(Bt + (wn * 64 + j * 16 + l15) * 64 + ch);
#pragma unroll
            for (int i = 0; i < 4; ++i)
#pragma unroll
                for (int j = 0; j < 4; ++j)
                    acc[i][j] = __builtin_amdgcn_mfma_f32_16x16x32_bf16(af[i], bfr[j], acc[i][j], 0, 0, 0);
        }
    }

    // epilogue: acc (row=quad*4+r, col=l15) -> LDS bf16 -> coalesced short8 stores
    __syncthreads();
#pragma unroll
    for (int i = 0; i < 4; ++i)
#pragma unroll
        for (int j = 0; j < 4; ++j) {
            int row = wm * 64 + i * 16 + quad * 4;
            int col = wn * 64 + j * 16 + l15;
#pragma unroll
            for (int r = 0; r < 4; ++r)
                lds[(row + r) * 136 + col] = f2bf(acc[i][j][r]);
        }
    __syncthreads();
    for (int c = t; c < 128 * 16; c += 256) {
        int row = c >> 4, ch2 = c & 15;
        int grow = mbase + row;
        if (grow < N_NODES)
            *(short8*)(ZW + (size_t)grow * 512 + nbase + ch2 * 8) =
                *(const short8*)(lds + row * 136 + ch2 * 8);
    }
}

// ---------------- stage 2: pipelined gather+bias+ReLU -> h ; out = h @ W2^T + b2 ------------
// NT=8 tiles of EBLK=32 edges per block. Raw s_barrier (LDS-drain only) keeps the next tile's
// gathers in flight across MFMA+epilogue; sched_barrier(0) pins the issue points so the
// register allocator cannot re-fold the pipeline (round-2 lesson: VGPR=52 proved it did).
// W2 fragments persistent in 64 VGPRs (verified 16x16 layouts; zero per-tile B traffic).
#define H_PITCH 264
#define EBLK 32
#define NT 8
__launch_bounds__(256, 3)
__global__ void stage2_kernel(const int* __restrict__ eidx, const unsigned short* __restrict__ ZW,
                              const float* __restrict__ b1, const unsigned short* __restrict__ w2b,
                              const float* __restrict__ b2, float* __restrict__ out) {
    __shared__ unsigned short h[EBLK * H_PITCH];   // 16896 B; reused as [32][132] f32 for epilogue
    __shared__ int idx2[512];                      // src[0..255], dst[256..511]
    float* hf = (float*)h;

    const int t    = threadIdx.x;
    const int lane = t & 63, wave = t >> 6;
    const int lj = lane & 31, hi = lane >> 5;      // gather lane split: 32 lanes x 16B, 2 rows/inst
    const int l15 = lane & 15, quad = lane >> 4;   // MFMA lane split
    const int w8 = wave * 8;
    const int eb0 = blockIdx.x * (EBLK * NT);

    {   // stage all 256 edge indices (src+dst), coalesced
        int e = eb0 + t; if (e >= N_EDGES) e = N_EDGES - 1;
        idx2[t]       = eidx[e];
        idx2[256 + t] = eidx[N_EDGES + e];
    }
    __syncthreads();

    // persistent W2 fragments: bfrag[jj][kk] = w2b[wave*32 + jj*16 + l15][kk*32 + quad*8 ..+8]
    short8 bfrag[2][8];
#pragma unroll
    for (int jj = 0; jj < 2; ++jj)
#pragma unroll
        for (int kk = 0; kk < 8; ++kk)
            bfrag[jj][kk] = *(const short8*)(w2b + (size_t)(wave * 32 + jj * 16 + l15) * 256
                                             + kk * 32 + quad * 8);

    float4v b1a = *(const float4v*)(b1 + lj * 8);
    float4v b1b = *(const float4v*)(b1 + lj * 8 + 4);
    float b2r[2];
#pragma unroll
    for (int jj = 0; jj < 2; ++jj) b2r[jj] = b2[wave * 32 + jj * 16 + l15];
    const unsigned short* zs = ZW + lj * 8;
    const unsigned short* zd = ZW + 256 + lj * 8;

    // issue tile-0 gathers (8 per wave; rows w8..w8+7 of the tile)
    short8 va[4], vb[4];
#pragma unroll
    for (int p = 0; p < 4; ++p) {
        int r = w8 + p * 2 + hi;
        va[p] = *(const short8*)(zs + (size_t)idx2[r] * 512);
        vb[p] = *(const short8*)(zd + (size_t)idx2[256 + r] * 512);
    }
    __builtin_amdgcn_sched_barrier(0);

    for (int tt = 0; tt < NT; ++tt) {
        const int tb = tt * 32;
        // ---- P1: convert tile tt (vmcnt auto-wait on va/vb) -> h bf16
#pragma unroll
        for (int p = 0; p < 4; ++p) {
            int r = w8 + p * 2 + hi;
            short8 xa = va[p], xb = vb[p];
            short8 rv;
#pragma unroll
            for (int i = 0; i < 8; ++i) {
                float v = bf2f((unsigned short)xa[i]) + bf2f((unsigned short)xb[i])
                        + ((i < 4) ? b1a[i] : b1b[i - 4]);
                v = v > 0.f ? v : 0.f;
                rv[i] = (short)f2bf(v);
            }
            *(short8*)(h + r * H_PITCH + lj * 8) = rv;
        }
        // ---- P2: issue next tile's gathers; they stay in flight through MFMA+epilogue
        if (tt + 1 < NT) {
            const int tb2 = tb + 32;
#pragma unroll
            for (int p = 0; p < 4; ++p) {
                int r = tb2 + w8 + p * 2 + hi;
                va[p] = *(const short8*)(zs + (size_t)idx2[r] * 512);
                vb[p] = *(const short8*)(zd + (size_t)idx2[256 + r] * 512);
            }
        }
        __builtin_amdgcn_sched_barrier(0);
        // ---- P3: h ready. Raw barrier: drain LDS only, NOT vmcnt (gathers keep flying)
        asm volatile("s_waitcnt lgkmcnt(0)" ::: "memory");
        __builtin_amdgcn_s_barrier();
        __builtin_amdgcn_sched_barrier(0);
        // ---- P4: MFMA  (A rows 0..31 from h; B persistent in regs)
        float4v acc[2][2];
        const float4v fz = {0.f, 0.f, 0.f, 0.f};
        acc[0][0] = fz; acc[0][1] = fz; acc[1][0] = fz; acc[1][1] = fz;
#pragma unroll
        for (int kk = 0; kk < 8; ++kk) {
            short8 af0 = *(const short8*)(h + (l15)      * H_PITCH + kk * 32 + quad * 8);
            short8 af1 = *(const short8*)(h + (16 + l15) * H_PITCH + kk * 32 + quad * 8);
            acc[0][0] = __builtin_amdgcn_mfma_f32_16x16x32_bf16(af0, bfrag[0][kk], acc[0][0], 0, 0, 0);
            acc[0][1] = __builtin_amdgcn_mfma_f32_16x16x32_bf16(af0, bfrag[1][kk], acc[0][1], 0, 0, 0);
            acc[1][0] = __builtin_amdgcn_mfma_f32_16x16x32_bf16(af1, bfrag[0][kk], acc[1][0], 0, 0, 0);
            acc[1][1] = __builtin_amdgcn_mfma_f32_16x16x32_bf16(af1, bfrag[1][kk], acc[1][1], 0, 0, 0);
        }
        // ---- P5: all h reads done (consumed by MFMA before barrier)
        __builtin_amdgcn_sched_barrier(0);
        __builtin_amdgcn_s_barrier();
        __builtin_amdgcn_sched_barrier(0);
        // ---- P6: acc + b2 -> hf (f32 reuse of h region)
#pragma unroll
        for (int jj = 0; jj < 2; ++jj)
#pragma unroll
            for (int i = 0; i < 2; ++i)
#pragma unroll
                for (int r = 0; r < 4; ++r)
                    hf[(i * 16 + quad * 4 + r) * 132 + wave * 32 + jj * 16 + l15] =
                        acc[i][jj][r] + b2r[jj];
        // ---- P7: hf complete
        asm volatile("s_waitcnt lgkmcnt(0)" ::: "memory");
        __builtin_amdgcn_s_barrier();
        __builtin_amdgcn_sched_barrier(0);
        // ---- P8: coalesced nontemporal stores (32 rows x 512B)
#pragma unroll
        for (int pass = 0; pass < 4; ++pass) {
            int it = pass * 256 + t;
            int row = it >> 5, c4 = (it & 31) * 4;
            int e = eb0 + tb + row;
            if (e < N_EDGES) {
                float4v v = *(const float4v*)(hf + row * 132 + c4);
                __builtin_nontemporal_store(v, (float4v*)(out + (size_t)e * 128 + c4));
            }
        }
        // ---- P9: hf reads consumed (lgkm waits precede the stores) -> h free for next tile
        __builtin_amdgcn_sched_barrier(0);
        __builtin_amdgcn_s_barrier();
        __builtin_amdgcn_sched_barrier(0);
    }
}

// ---------------- fallback (ws too small): exact fp32 ----------------
__global__ void fallback_kernel(const float* __restrict__ z, const int* __restrict__ eidx,
                                const float* __restrict__ W1, const float* __restrict__ b1,
                                const float* __restrict__ W2, const float* __restrict__ b2,
                                float* __restrict__ out) {
    __shared__ float zs[512];
    __shared__ float hh[256];
    int e = blockIdx.x, t = threadIdx.x;
    int s = eidx[e], d = eidx[N_EDGES + e];
    zs[t]       = z[(size_t)s * 256 + t];
    zs[256 + t] = z[(size_t)d * 256 + t];
    __syncthreads();
    float a = b1[t];
    const float* wr = W1 + (size_t)t * 512;
    for (int k = 0; k < 512; ++k) a += zs[k] * wr[k];
    hh[t] = a > 0.f ? a : 0.f;
    __syncthreads();
    if (t < 128) {
        float o = b2[t];
        const float* w2r = W2 + (size_t)t * 256;
        for (int k = 0; k < 256; ++k) o += hh[k] * w2r[k];
        out[(size_t)e * 128 + t] = o;
    }
}

extern "C" void kernel_launch(void* const* d_in, const int* in_sizes, int n_in,
                              void* d_out, int out_size, void* d_ws, size_t ws_size,
                              hipStream_t stream) {
    const float* z    = (const float*)d_in[0];
    const int*   eidx = (const int*)d_in[1];
    const float* W1   = (const float*)d_in[2];
    const float* b1   = (const float*)d_in[3];
    const float* W2   = (const float*)d_in[4];
    const float* b2   = (const float*)d_in[5];
    float* out = (float*)d_out;

    const size_t zw_bytes = (size_t)N_NODES * 512 * 2;          // 102,400,000
    const size_t w1c_off  = zw_bytes;
    const size_t w2b_off  = w1c_off + (size_t)512 * 256 * 2;
    const size_t need     = w2b_off + (size_t)128 * 256 * 2;

    if (ws_size < need) {
        fallback_kernel<<<N_EDGES, 256, 0, stream>>>(z, eidx, W1, b1, W2, b2, out);
        return;
    }
    unsigned short* ZW  = (unsigned short*)d_ws;
    unsigned short* w1c = (unsigned short*)((char*)d_ws + w1c_off);
    unsigned short* w2b = (unsigned short*)((char*)d_ws + w2b_off);
    // zb scratch lives in d_out (51.2MB of 256MB); consumed by stage1 before stage2 writes out
    unsigned short* zb  = (unsigned short*)d_out;

    zconv_kernel<<<12500, 256, 0, stream>>>(z, zb);
    prep_kernel<<<640, 256, 0, stream>>>(W1, W2, w1c, w2b);
    stage1_kernel<<<dim3(782, 4), 256, 0, stream>>>(zb, w1c, ZW);
    const int s2_blocks = (N_EDGES + EBLK * NT - 1) / (EBLK * NT);   // 1954
    stage2_kernel<<<s2_blocks, 256, 0, stream>>>(eidx, ZW, b1, w2b, b2, out);
}